// Round 9
// baseline (151.239 us; speedup 1.0000x reference)
//
#include <hip/hip_runtime.h>

#define DIM 8192
#define BATCH 256
#define BN 32
#define BK 64
#define KSPLIT 4
#define KLEN (DIM / KSPLIT)   // 2048 k per block
#define NSTEP (KLEN / BK)     // 32 steps
#define NTT (DIM / BN)        // 256 n-tiles

typedef __attribute__((ext_vector_type(8))) short   short8;   // 8 bf16 frag
typedef __attribute__((ext_vector_type(4))) float   f32x4;
typedef __attribute__((ext_vector_type(4))) unsigned short u16x4;

__device__ __forceinline__ unsigned short f2b(float f) {
    unsigned u = __builtin_bit_cast(unsigned, f);
    u = (u + 0x7FFFu + ((u >> 16) & 1u)) >> 16;
    return (unsigned short)u;
}

// ---- prepass: x f32 -> bf16 (ws+0, 4 MB) ----
__global__ __launch_bounds__(512) void cvt_x_kernel(const float* __restrict__ x,
                                                    unsigned short* __restrict__ xb) {
    int i = blockIdx.x * 512 + threadIdx.x;
    f32x4 v = reinterpret_cast<const f32x4*>(x)[i];
    u16x4 o;
    o[0] = f2b(v[0]); o[1] = f2b(v[1]); o[2] = f2b(v[2]); o[3] = f2b(v[3]);
    reinterpret_cast<u16x4*>(xb)[i] = o;
}

// LDS 16B-slot swizzle (R5-verified conflict-free scheme)
__device__ __forceinline__ int F(int s) { return s ^ ((s >> 4) & 7); }

// ---- GEMM partials: p[ks][b][i] = sum_{j in ks-quarter} U[i,j]*x[b,j] ----
// grid 1024 = 256 n-tiles x 4 k-quarters -> 4 blocks/CU (4 independent barrier
// groups: m114 inter-block overlap hides each block's barrier drain).
// 256 threads (4 waves). BM=256 (U read exactly once), BN=32, BK=64.
// Wave w owns batch rows [64w, 64w+64): acc = 4(mf) x 2(nf) frags.
// Simple R5-style body: plain __syncthreads, compiler-scheduled waits.
__global__ __launch_bounds__(256, 4) void gemm_kernel(const unsigned short* __restrict__ xb,
                                                      const float* __restrict__ U,
                                                      float* __restrict__ part) {
    __shared__ unsigned short Blds[2][4 * 512];   // 2 bufs x 4KB, frag-linear

    const int tid  = threadIdx.x;
    const int lane = tid & 63;
    const int w    = tid >> 6;          // 0..3

    // XCD swizzle: bid&7 -> XCD; ks = (bid&7)>>1: each XCD serves one ks
    // (1MB xb k-slab resident in its 4MB L2); nt split across the pair.
    const int bid = blockIdx.x;
    const int x8  = bid & 7;
    const int ks  = x8 >> 1;
    const int nt  = (x8 & 1) * 128 + (bid >> 3);   // 0..255
    const int n0    = nt * BN;
    const int kbase = ks * KLEN;

    // --- B stager: thread -> (U-row r of 32, k-oct k8 of 8): 8 consecutive f32
    const int r  = tid >> 3;            // 0..31
    const int k8 = (tid & 7) * 8;       // 0..56
    const float* Up = U + (long)(n0 + r) * DIM + kbase + k8;   // + t*BK
    // frag id fb = nf*2 + h, nf = col/16, h = k/32; lane-in-frag = (r&15)+16*((k>>3)&3)
    const int wslot = F(((r >> 4) * 2 + (k8 >> 5)) * 64 + (r & 15) + 16 * ((k8 >> 3) & 3));

    // --- A frags: lane l -> batch row 64w + mf*16 + (l&15), k = h*32 + (l>>4)*8
    const unsigned short* Ap = xb + (long)(64 * w + (lane & 15)) * DIM + kbase + (lane >> 4) * 8;

    // --- B frag read slots (16B units)
    int rslot[2][2];
#pragma unroll
    for (int nf = 0; nf < 2; ++nf)
#pragma unroll
        for (int h = 0; h < 2; ++h)
            rslot[nf][h] = F((nf * 2 + h) * 64 + lane);

    f32x4 acc[4][2];
#pragma unroll
    for (int mf = 0; mf < 4; ++mf)
#pragma unroll
        for (int nf = 0; nf < 2; ++nf)
            acc[mf][nf] = (f32x4){0.f, 0.f, 0.f, 0.f};

    f32x4 UpreA[2], UpreB[2];   // U(s): even s in A at odd steps... parity slots

    // ---- prologue: U(0) -> buf0 directly; U(1) -> UpreB
    {
        f32x4 u0 = *(const f32x4*)(Up);
        f32x4 u1 = *(const f32x4*)(Up + 4);
        UpreB[0] = *(const f32x4*)(Up + BK);
        UpreB[1] = *(const f32x4*)(Up + BK + 4);
        short8 pk;
#pragma unroll
        for (int j = 0; j < 4; ++j) { pk[j] = (short)f2b(u0[j]); pk[j + 4] = (short)f2b(u1[j]); }
        *(short8*)&Blds[0][wslot * 8] = pk;
    }
    __syncthreads();

    // step T (P = T&1): load U(T+2) -> Upre[P], A(T);
    // cvt+ds_write U(T+1) (in Upre[P^1]) -> buf P^1; ds_read B(T) from buf P;
    // MFMA; __syncthreads.
#define STEPBODY(T, P, UIN, UOUT)                                                    \
    do {                                                                             \
        { int tp = ((T) + 2 < NSTEP) ? (T) + 2 : NSTEP - 1;                          \
          UIN[0] = *(const f32x4*)(Up + tp * BK);                                    \
          UIN[1] = *(const f32x4*)(Up + tp * BK + 4); }                              \
        short8 A[4][2];                                                              \
        _Pragma("unroll")                                                            \
        for (int mf = 0; mf < 4; ++mf)                                               \
            _Pragma("unroll")                                                        \
            for (int h = 0; h < 2; ++h)                                              \
                A[mf][h] = *(const short8*)(Ap + (T) * BK + mf * 16 * DIM + h * 32); \
        {                                                                            \
            short8 pk;                                                               \
            _Pragma("unroll")                                                        \
            for (int j = 0; j < 4; ++j) {                                            \
                pk[j]     = (short)f2b(UOUT[0][j]);                                  \
                pk[j + 4] = (short)f2b(UOUT[1][j]);                                  \
            }                                                                        \
            *(short8*)&Blds[(P) ^ 1][wslot * 8] = pk;                                \
        }                                                                            \
        _Pragma("unroll")                                                            \
        for (int h = 0; h < 2; ++h) {                                                \
            short8 B0 = *(const short8*)&Blds[P][rslot[0][h] * 8];                   \
            short8 B1 = *(const short8*)&Blds[P][rslot[1][h] * 8];                   \
            _Pragma("unroll")                                                        \
            for (int mf = 0; mf < 4; ++mf) {                                         \
                acc[mf][0] = __builtin_amdgcn_mfma_f32_16x16x32_bf16(                \
                    A[mf][h], B0, acc[mf][0], 0, 0, 0);                              \
                acc[mf][1] = __builtin_amdgcn_mfma_f32_16x16x32_bf16(                \
                    A[mf][h], B1, acc[mf][1], 0, 0, 0);                              \
            }                                                                        \
        }                                                                            \
        __syncthreads();                                                             \
    } while (0)

    for (int tt = 0; tt < NSTEP; tt += 2) {
        STEPBODY(tt,     0, UpreA, UpreB);   // even: read buf0, write buf1, consume U(T+1)=UpreB
        STEPBODY(tt + 1, 1, UpreB, UpreA);   // odd:  read buf1, write buf0, consume UpreA
    }
#undef STEPBODY

    // ---- partial store: D row=(l>>4)*4+reg, col=l&15 (verified mapping)
    float* p = part + (long)ks * (BATCH * DIM);
    const int prow0 = 64 * w + (lane >> 4) * 4;
    const int pcol0 = n0 + (lane & 15);
#pragma unroll
    for (int mf = 0; mf < 4; ++mf)
#pragma unroll
        for (int nf = 0; nf < 2; ++nf) {
            float* o = p + (long)(prow0 + mf * 16) * DIM + pcol0 + nf * 16;
#pragma unroll
            for (int rr = 0; rr < 4; ++rr)
                o[(long)rr * DIM] = acc[mf][nf][rr];
        }
}

// ---- reduce: out = p0 + p1 + p2 + p3 ----
__global__ __launch_bounds__(512) void reduce_kernel(const float* __restrict__ part,
                                                     float* __restrict__ out) {
    long i = (long)blockIdx.x * 512 + threadIdx.x;   // f32x4 index, 524288 total
    const f32x4* p0 = reinterpret_cast<const f32x4*>(part);
    const f32x4* p1 = p0 + (long)BATCH * DIM / 4;
    const f32x4* p2 = p1 + (long)BATCH * DIM / 4;
    const f32x4* p3 = p2 + (long)BATCH * DIM / 4;
    f32x4 v = p0[i] + p1[i] + p2[i] + p3[i];
    reinterpret_cast<f32x4*>(out)[i] = v;
}

extern "C" void kernel_launch(void* const* d_in, const int* in_sizes, int n_in,
                              void* d_out, int out_size, void* d_ws, size_t ws_size,
                              hipStream_t stream) {
    const float* x = (const float*)d_in[0];     // [256, 8192] f32
    const float* U = (const float*)d_in[1];     // [8192, 8192] f32
    float* outp = (float*)d_out;                // [256, 8192] f32

    unsigned short* xb = (unsigned short*)d_ws;                    // 4 MB
    float* part = (float*)((char*)d_ws + (size_t)BATCH * DIM * 2); // 32 MB

    cvt_x_kernel<<<(BATCH * DIM / 4) / 512, 512, 0, stream>>>(x, xb);
    gemm_kernel<<<NTT * KSPLIT, 256, 0, stream>>>(xb, U, part);
    reduce_kernel<<<(BATCH * DIM / 4) / 512, 512, 0, stream>>>(part, outp);
}

// Round 10
// 114.456 us; speedup vs baseline: 1.3214x; 1.3214x over previous
//
#include <hip/hip_runtime.h>

#define DIM 8192
#define BATCH 256
#define BN 256
#define BK 32
#define KSPLIT 8
#define KLEN (DIM / KSPLIT)   // 1024 k per block
#define NSTEP (KLEN / BK)     // 32 steps
#define NTILE (DIM / BN)      // 32 n-tiles

typedef __attribute__((ext_vector_type(8))) short   short8;   // 8 bf16 frag
typedef __attribute__((ext_vector_type(4))) float   f32x4;
typedef __attribute__((ext_vector_type(4))) unsigned short u16x4;

__device__ __forceinline__ unsigned short f2b(float f) {
    unsigned u = __builtin_bit_cast(unsigned, f);
    u = (u + 0x7FFFu + ((u >> 16) & 1u)) >> 16;
    return (unsigned short)u;
}

// ---- prepass: x f32 -> bf16 (ws+0, 4 MB) ----
__global__ __launch_bounds__(512) void cvt_x_kernel(const float* __restrict__ x,
                                                    unsigned short* __restrict__ xb) {
    int i = blockIdx.x * 512 + threadIdx.x;
    f32x4 v = reinterpret_cast<const f32x4*>(x)[i];
    u16x4 o;
    o[0] = f2b(v[0]); o[1] = f2b(v[1]); o[2] = f2b(v[2]); o[3] = f2b(v[3]);
    reinterpret_cast<u16x4*>(xb)[i] = o;
}

// LDS 16B-slot swizzle (2-way max on both sides -> free, m136)
__device__ __forceinline__ int F(int s) { return s ^ ((s >> 4) & 7); }

// ---- GEMM partials: p[ks][b][i] = sum_{j in ks-eighth} U[i,j]*x[b,j] ----
// 256 blocks (32 nt x 8 ks; ks = bid&7 -> one ks per XCD), 512 thr (8 waves).
// BM=256 (full batch; U read EXACTLY once), BN=256 -> A-traffic 128 MB total.
// U streams straight into B-frag registers (128B/row = 1 cache line, dist-2
// prefetch, barrier-independent). Only x (16 KB/step, L2) stages via LDS.
// Wave w: cols [n0+32w, n0+32w+32) (2 nf frags) x all 256 batch (16 a frags).
__global__ __launch_bounds__(512, 2) void gemm_kernel(const unsigned short* __restrict__ xb,
                                                      const float* __restrict__ U,
                                                      float* __restrict__ part) {
    __shared__ unsigned short Ald[2][1024 * 8];   // 2 bufs x 16 KB, frag-linear

    const int tid  = threadIdx.x;
    const int lane = tid & 63;
    const int w    = tid >> 6;

    const int bid = blockIdx.x;
    const int ks  = bid & 7;          // XCD id == ks: xb k-slab (512 KB) L2-resident
    const int nt  = bid >> 3;         // 0..31
    const int n0    = nt * BN;
    const int kb    = ks * KLEN;

    // --- A stager: thread handles slots s0=tid, s1=tid+512.
    // slot s -> row = 16*(s>>6) + (s&15), kof = ((s>>4)&3)*8  (bijective)
    const int s0 = tid, s1 = tid + 512;
    const unsigned short* Asrc0 =
        xb + (long)(16 * (s0 >> 6) + (s0 & 15)) * DIM + kb + ((s0 >> 4) & 3) * 8;
    const unsigned short* Asrc1 =
        xb + (long)(16 * (s1 >> 6) + (s1 & 15)) * DIM + kb + ((s1 >> 4) & 3) * 8;
    const int wsl0 = F(s0) * 8, wsl1 = F(s1) * 8;   // ushort offsets

    // --- B (U) frag pointers: nf in {0,1}: row = n0+32w+16nf+(lane&15),
    //     k = kb + t*32 + (lane>>4)*8  (4 lanes/row -> 128B contiguous per row)
    const float* Ubp0 = U + (long)(n0 + 32 * w + (lane & 15)) * DIM + kb + (lane >> 4) * 8;
    const float* Ubp1 = Ubp0 + (long)16 * DIM;

    f32x4 acc[16][2];
#pragma unroll
    for (int a = 0; a < 16; ++a) {
        acc[a][0] = (f32x4){0.f, 0.f, 0.f, 0.f};
        acc[a][1] = (f32x4){0.f, 0.f, 0.f, 0.f};
    }

    // U parity prefetch: even steps consume/reload UeX, odd steps UoX. [nf][half]
    f32x4 Ue[2][2], Uo[2][2];

    // ---- prologue: U(0)->Ue, U(1)->Uo, A(0)->LDS buf0
    Ue[0][0] = *(const f32x4*)(Ubp0);      Ue[0][1] = *(const f32x4*)(Ubp0 + 4);
    Ue[1][0] = *(const f32x4*)(Ubp1);      Ue[1][1] = *(const f32x4*)(Ubp1 + 4);
    Uo[0][0] = *(const f32x4*)(Ubp0 + BK); Uo[0][1] = *(const f32x4*)(Ubp0 + BK + 4);
    Uo[1][0] = *(const f32x4*)(Ubp1 + BK); Uo[1][1] = *(const f32x4*)(Ubp1 + BK + 4);
    {
        short8 g0 = *(const short8*)(Asrc0);
        short8 g1 = *(const short8*)(Asrc1);
        *(short8*)&Ald[0][wsl0] = g0;
        *(short8*)&Ald[0][wsl1] = g1;
    }
    __syncthreads();

    // step T (P=T&1): load A(T+1); cvt B(T) from UC; reload UC with U(T+2);
    // 16 x {ds_read A-frag, 2 MFMA}; ds_write A(T+1) -> buf P^1; barrier.
#define STEPBODY(T, P, UC)                                                           \
    do {                                                                             \
        const int ta = ((T) + 1 < NSTEP) ? (T) + 1 : NSTEP - 1;                      \
        short8 g0 = *(const short8*)(Asrc0 + ta * BK);                               \
        short8 g1 = *(const short8*)(Asrc1 + ta * BK);                               \
        short8 Bf0, Bf1;                                                             \
        _Pragma("unroll")                                                            \
        for (int j = 0; j < 4; ++j) {                                                \
            Bf0[j] = (short)f2b(UC[0][0][j]); Bf0[j + 4] = (short)f2b(UC[0][1][j]);  \
            Bf1[j] = (short)f2b(UC[1][0][j]); Bf1[j + 4] = (short)f2b(UC[1][1][j]);  \
        }                                                                            \
        const int tp = ((T) + 2 < NSTEP) ? (T) + 2 : NSTEP - 1;                      \
        UC[0][0] = *(const f32x4*)(Ubp0 + tp * BK);                                  \
        UC[0][1] = *(const f32x4*)(Ubp0 + tp * BK + 4);                              \
        UC[1][0] = *(const f32x4*)(Ubp1 + tp * BK);                                  \
        UC[1][1] = *(const f32x4*)(Ubp1 + tp * BK + 4);                              \
        _Pragma("unroll")                                                            \
        for (int a = 0; a < 16; ++a) {                                               \
            short8 Af = *(const short8*)&Ald[P][F(a * 64 + lane) * 8];               \
            acc[a][0] = __builtin_amdgcn_mfma_f32_16x16x32_bf16(Af, Bf0, acc[a][0], 0, 0, 0); \
            acc[a][1] = __builtin_amdgcn_mfma_f32_16x16x32_bf16(Af, Bf1, acc[a][1], 0, 0, 0); \
        }                                                                            \
        *(short8*)&Ald[(P) ^ 1][wsl0] = g0;                                          \
        *(short8*)&Ald[(P) ^ 1][wsl1] = g1;                                          \
        __syncthreads();                                                             \
    } while (0)

    for (int tt = 0; tt < NSTEP; tt += 2) {
        STEPBODY(tt,     0, Ue);
        STEPBODY(tt + 1, 1, Uo);
    }
#undef STEPBODY

    // ---- partial store: D row=(l>>4)*4+reg -> batch, col=l&15 (verified)
    float* p = part + (long)ks * (BATCH * DIM);
    const int pcol = n0 + 32 * w + (lane & 15);
#pragma unroll
    for (int a = 0; a < 16; ++a) {
        const int prow = 16 * a + (lane >> 4) * 4;
#pragma unroll
        for (int nf = 0; nf < 2; ++nf) {
            float* o = p + (long)prow * DIM + pcol + nf * 16;
#pragma unroll
            for (int rr = 0; rr < 4; ++rr)
                o[(long)rr * DIM] = acc[a][nf][rr];
        }
    }
}

// ---- reduce: out = sum of 8 partials ----
__global__ __launch_bounds__(512) void reduce_kernel(const float* __restrict__ part,
                                                     float* __restrict__ out) {
    long i = (long)blockIdx.x * 512 + threadIdx.x;   // f32x4 index, 524288 total
    const long stride = (long)BATCH * DIM / 4;
    const f32x4* p = reinterpret_cast<const f32x4*>(part);
    f32x4 v = p[i];
#pragma unroll
    for (int s = 1; s < KSPLIT; ++s) v += p[i + s * stride];
    reinterpret_cast<f32x4*>(out)[i] = v;
}

extern "C" void kernel_launch(void* const* d_in, const int* in_sizes, int n_in,
                              void* d_out, int out_size, void* d_ws, size_t ws_size,
                              hipStream_t stream) {
    const float* x = (const float*)d_in[0];     // [256, 8192] f32
    const float* U = (const float*)d_in[1];     // [8192, 8192] f32
    float* outp = (float*)d_out;                // [256, 8192] f32

    unsigned short* xb = (unsigned short*)d_ws;                    // 4 MB
    float* part = (float*)((char*)d_ws + (size_t)BATCH * DIM * 2); // 64 MB (8 partials)

    cvt_x_kernel<<<(BATCH * DIM / 4) / 512, 512, 0, stream>>>(x, xb);
    gemm_kernel<<<NTILE * KSPLIT, 512, 0, stream>>>(xb, U, part);
    reduce_kernel<<<(BATCH * DIM / 4) / 512, 512, 0, stream>>>(part, outp);
}

// Round 11
// 105.095 us; speedup vs baseline: 1.4391x; 1.0891x over previous
//
#include <hip/hip_runtime.h>

#define DIM 8192
#define BATCH 256
#define BN 128
#define BK 32
#define KSPLIT 4
#define KLEN (DIM / KSPLIT)   // 2048 k per block
#define NSTEP (KLEN / BK)     // 64 steps
#define LDSBUF 32768          // per-buffer: A 16 KB (bf16) + B 16 KB (f32)

typedef __attribute__((ext_vector_type(8))) short   short8;   // 8 bf16 frag
typedef __attribute__((ext_vector_type(4))) float   f32x4;
typedef __attribute__((ext_vector_type(4))) unsigned short u16x4;

__device__ __forceinline__ unsigned short f2b(float f) {
    unsigned u = __builtin_bit_cast(unsigned, f);
    u = (u + 0x7FFFu + ((u >> 16) & 1u)) >> 16;
    return (unsigned short)u;
}

// ---- prepass: x f32 -> bf16 (ws+0, 4 MB) ----
__global__ __launch_bounds__(512) void cvt_x_kernel(const float* __restrict__ x,
                                                    unsigned short* __restrict__ xb) {
    int i = blockIdx.x * 512 + threadIdx.x;
    f32x4 v = reinterpret_cast<const f32x4*>(x)[i];
    u16x4 o;
    o[0] = f2b(v[0]); o[1] = f2b(v[1]); o[2] = f2b(v[2]); o[3] = f2b(v[3]);
    reinterpret_cast<u16x4*>(xb)[i] = o;
}

// ---- GEMM partials: p[ks][b][i] = sum_{j in ks-quarter} U[i,j]*x[b,j] ----
// 256 blocks (64 nt x 4 ks), 512 thr (8 waves: 2m x 4n). BM=256 (U read once),
// BN=128, BK=32. ZERO register global loads in the K-loop: A (xb bf16) and B
// (U f32) are DMA'd by global_load_lds into FRAG-LINEAR LDS (per-lane source
// addressing = m173 pre-swizzle; ds_read_b128 at lane*16 is conflict-free by
// construction). 4 buffers, distance-3, one counted vmcnt(8) + raw s_barrier
// per step: every DMA has ~3 bodies of slack; vmcnt FIFO stays 12 deep.
__global__ __launch_bounds__(512) void gemm_kernel(const unsigned short* __restrict__ xb,
                                                   const float* __restrict__ U,
                                                   float* __restrict__ part) {
    __shared__ unsigned char lds[4][LDSBUF];

    const int tid  = threadIdx.x;
    const int lane = tid & 63;
    const int w    = tid >> 6;
    const int wm   = w >> 2;      // 0..1: batch half
    const int wn   = w & 3;       // 0..3: 32-col slice

    // XCD pinning: x8 = bid&7 -> XCD; ks = x8>>1 (1 MB xb k-slab per L2)
    const int bid = blockIdx.x;
    const int x8  = bid & 7;
    const int ks  = x8 >> 1;
    const int nt  = (x8 & 1) * 32 + (bid >> 3);   // 0..63
    const int n0  = nt * BN;
    const int kb  = ks * KLEN;

    // --- staging chunks: c = 4w+j; c<16: A-frag c (1 KB bf16, 16 batch rows x
    // 32 k); c>=16: B-piece (nfg,q) (1 KB f32, 16 U-rows x 4-of-8 k). Lane l
    // sources exactly the 16 B that frag-slot l consumes.
    const char* sbase[4];
    int soff[4], sstr[4];
#pragma unroll
    for (int j = 0; j < 4; ++j) {
        const int c = 4 * w + j;
        if (c < 16) {
            sbase[j] = (const char*)(xb + (long)(16 * c + (lane & 15)) * DIM
                                        + kb + (lane >> 4) * 8);
            soff[j] = c * 1024;
            sstr[j] = BK * 2;     // bytes per k-step (bf16)
        } else {
            const int cc = c - 16, nfg = cc >> 1, q = cc & 1;
            sbase[j] = (const char*)(U + (long)(n0 + 16 * nfg + (lane & 15)) * DIM
                                       + kb + (lane >> 4) * 8 + q * 4);
            soff[j] = 16384 + cc * 1024;
            sstr[j] = BK * 4;     // bytes per k-step (f32)
        }
    }

#define STAGE(TS, BUF)                                                               \
    do {                                                                             \
        _Pragma("unroll")                                                            \
        for (int j = 0; j < 4; ++j)                                                  \
            __builtin_amdgcn_global_load_lds(                                        \
                (const __attribute__((address_space(1))) void*)(sbase[j] + (long)(TS) * sstr[j]), \
                (__attribute__((address_space(3))) void*)&lds[BUF][soff[j] + lane * 16],          \
                16, 0, 0);                                                           \
    } while (0)

    f32x4 acc[8][2];
#pragma unroll
    for (int i = 0; i < 8; ++i) {
        acc[i][0] = (f32x4){0.f, 0.f, 0.f, 0.f};
        acc[i][1] = (f32x4){0.f, 0.f, 0.f, 0.f};
    }

    // ---- prologue: fill 3 buffers; wait for buf0 (retire oldest 4 of 12)
    STAGE(0, 0);
    STAGE(1, 1);
    STAGE(2, 2);
    asm volatile("s_waitcnt vmcnt(8)" ::: "memory");
    __builtin_amdgcn_s_barrier();
    asm volatile("" ::: "memory");

    for (int t = 0; t < NSTEP; ++t) {
        const int buf = t & 3;
        const int ts  = (t + 3 < NSTEP) ? t + 3 : NSTEP - 1;
        STAGE(ts, (t + 3) & 3);              // overwrites buf read at step t-1
        __builtin_amdgcn_sched_barrier(0);

        const char* La = (const char*)&lds[buf][0];
        const char* Lb = (const char*)&lds[buf][16384];

        // B frags: 2 x (2 ds_read_b128 f32 + cvt to bf16)
        short8 Bf[2];
#pragma unroll
        for (int nf = 0; nf < 2; ++nf) {
            const int nfg = wn * 2 + nf;
            f32x4 q0 = *(const f32x4*)(Lb + (nfg * 2 + 0) * 1024 + lane * 16);
            f32x4 q1 = *(const f32x4*)(Lb + (nfg * 2 + 1) * 1024 + lane * 16);
#pragma unroll
            for (int jj = 0; jj < 4; ++jj) {
                Bf[nf][jj]     = (short)f2b(q0[jj]);
                Bf[nf][jj + 4] = (short)f2b(q1[jj]);
            }
        }
        __builtin_amdgcn_s_setprio(1);
#pragma unroll
        for (int i = 0; i < 8; ++i) {
            short8 Af = *(const short8*)(La + (8 * wm + i) * 1024 + lane * 16);
            acc[i][0] = __builtin_amdgcn_mfma_f32_16x16x32_bf16(Af, Bf[0], acc[i][0], 0, 0, 0);
            acc[i][1] = __builtin_amdgcn_mfma_f32_16x16x32_bf16(Af, Bf[1], acc[i][1], 0, 0, 0);
        }
        __builtin_amdgcn_s_setprio(0);

        // counted drain: retire stage(t+1) (3 bodies old); keep 8 in flight
        asm volatile("s_waitcnt vmcnt(8)" ::: "memory");
        __builtin_amdgcn_s_barrier();
        asm volatile("" ::: "memory");
    }
#undef STAGE

    // ---- partial store: D row=(l>>4)*4+rr -> batch, col=l&15 (verified)
    float* p = part + (long)ks * (BATCH * DIM);
    const int pcol = n0 + 32 * wn + (lane & 15);
#pragma unroll
    for (int i = 0; i < 8; ++i) {
        const int prow = 128 * wm + 16 * i + (lane >> 4) * 4;
#pragma unroll
        for (int nf = 0; nf < 2; ++nf) {
            float* o = p + (long)prow * DIM + pcol + nf * 16;
#pragma unroll
            for (int rr = 0; rr < 4; ++rr)
                o[(long)rr * DIM] = acc[i][nf][rr];
        }
    }
}

// ---- reduce: out = p0 + p1 + p2 + p3 ----
__global__ __launch_bounds__(512) void reduce_kernel(const float* __restrict__ part,
                                                     float* __restrict__ out) {
    long i = (long)blockIdx.x * 512 + threadIdx.x;   // f32x4 index, 524288 total
    const long stride = (long)BATCH * DIM / 4;
    const f32x4* p = reinterpret_cast<const f32x4*>(part);
    f32x4 v = p[i] + p[i + stride] + p[i + 2 * stride] + p[i + 3 * stride];
    reinterpret_cast<f32x4*>(out)[i] = v;
}

extern "C" void kernel_launch(void* const* d_in, const int* in_sizes, int n_in,
                              void* d_out, int out_size, void* d_ws, size_t ws_size,
                              hipStream_t stream) {
    const float* x = (const float*)d_in[0];     // [256, 8192] f32
    const float* U = (const float*)d_in[1];     // [8192, 8192] f32
    float* outp = (float*)d_out;                // [256, 8192] f32

    unsigned short* xb = (unsigned short*)d_ws;                    // 4 MB
    float* part = (float*)((char*)d_ws + (size_t)BATCH * DIM * 2); // 32 MB

    cvt_x_kernel<<<(BATCH * DIM / 4) / 512, 512, 0, stream>>>(x, xb);
    gemm_kernel<<<(DIM / BN) * KSPLIT, 512, 0, stream>>>(xb, U, part);
    reduce_kernel<<<(BATCH * DIM / 4) / 512, 512, 0, stream>>>(part, outp);
}

// Round 12
// 93.537 us; speedup vs baseline: 1.6169x; 1.1236x over previous
//
#include <hip/hip_runtime.h>

#define DIM 8192
#define BATCH 256
#define BN 256
#define BK 32
#define KSPLIT 8
#define KLEN (DIM / KSPLIT)   // 1024 k per block
#define NSTEP (KLEN / BK)     // 32 steps
#define NTILE (DIM / BN)      // 32 n-tiles
#define LDSBUF 49152          // per-buffer: A 16 KB (bf16) + B 32 KB (f32)

typedef __attribute__((ext_vector_type(8))) short   short8;   // 8 bf16 frag
typedef __attribute__((ext_vector_type(4))) float   f32x4;
typedef __attribute__((ext_vector_type(4))) unsigned short u16x4;
typedef __attribute__((ext_vector_type(8))) unsigned short u16x8;

__device__ __forceinline__ unsigned short f2b(float f) {
    unsigned u = __builtin_bit_cast(unsigned, f);
    u = (u + 0x7FFFu + ((u >> 16) & 1u)) >> 16;
    return (unsigned short)u;
}
__device__ __forceinline__ float b2f(unsigned short h) {
    unsigned u = ((unsigned)h) << 16;
    return __builtin_bit_cast(float, u);
}

// ---- prepass: x f32 -> bf16 (ws+0, 4 MB) ----
__global__ __launch_bounds__(512) void cvt_x_kernel(const float* __restrict__ x,
                                                    unsigned short* __restrict__ xb) {
    int i = blockIdx.x * 512 + threadIdx.x;
    f32x4 v = reinterpret_cast<const f32x4*>(x)[i];
    u16x4 o;
    o[0] = f2b(v[0]); o[1] = f2b(v[1]); o[2] = f2b(v[2]); o[3] = f2b(v[3]);
    reinterpret_cast<u16x4*>(xb)[i] = o;
}

// ---- GEMM partials (bf16): p[ks][b][i] = sum_{j in ks-eighth} U[i,j]*x[b,j]
// 256 blocks = 32 nt x 8 ks (ks = bid&7 -> one ks per XCD; 512 KB xb slab per
// L2). 512 thr (8 waves); BM=256 (U read exactly once), BN=256 -> A-traffic
// 128 MB total. All staging via global_load_lds into frag-linear LDS (lane-
// exact source addressing, conflict-free by construction). 3 buffers,
// distance-2, one counted vmcnt(6) + raw s_barrier per step. Per step/block:
// A 16 KB + U 32 KB = 48 chunks of 1 KB; wave w DMAs chunks 6w..6w+5.
// Wave w computes cols [n0+32w, n0+32w+32) x all 256 batch: acc 16a x 2nf.
__global__ __launch_bounds__(512) void gemm_kernel(const unsigned short* __restrict__ xb,
                                                   const float* __restrict__ U,
                                                   unsigned short* __restrict__ part) {
    __shared__ unsigned char lds[3][LDSBUF];

    const int tid  = threadIdx.x;
    const int lane = tid & 63;
    const int w    = tid >> 6;

    const int bid = blockIdx.x;
    const int ks  = bid & 7;
    const int nt  = bid >> 3;
    const int n0  = nt * BN;
    const int kb  = ks * KLEN;

    // --- staging chunks: c = 6w+j. c<16: A-frag c (16 batch rows x 32 k bf16).
    // c>=16: cc=c-16: B-piece (nfg=cc>>1, q=cc&1): 16 U-rows x 4-of-8 k (f32).
    const char* sbase[6];
    int soff[6], sstr[6];
#pragma unroll
    for (int j = 0; j < 6; ++j) {
        const int c = 6 * w + j;
        if (c < 16) {
            sbase[j] = (const char*)(xb + (long)(16 * c + (lane & 15)) * DIM
                                        + kb + (lane >> 4) * 8);
            soff[j] = c * 1024;
            sstr[j] = BK * 2;
        } else {
            const int cc = c - 16, nfg = cc >> 1, q = cc & 1;
            sbase[j] = (const char*)(U + (long)(n0 + 16 * nfg + (lane & 15)) * DIM
                                       + kb + (lane >> 4) * 8 + q * 4);
            soff[j] = 16384 + cc * 1024;
            sstr[j] = BK * 4;
        }
    }

#define STAGE(TS, BUF)                                                               \
    do {                                                                             \
        _Pragma("unroll")                                                            \
        for (int j = 0; j < 6; ++j)                                                  \
            __builtin_amdgcn_global_load_lds(                                        \
                (const __attribute__((address_space(1))) void*)(sbase[j] + (long)(TS) * sstr[j]), \
                (__attribute__((address_space(3))) void*)&lds[BUF][soff[j] + lane * 16],          \
                16, 0, 0);                                                           \
    } while (0)

    f32x4 acc[16][2];
#pragma unroll
    for (int a = 0; a < 16; ++a) {
        acc[a][0] = (f32x4){0.f, 0.f, 0.f, 0.f};
        acc[a][1] = (f32x4){0.f, 0.f, 0.f, 0.f};
    }

    // ---- prologue: fill bufs 0,1; retire stage(0)
    STAGE(0, 0);
    STAGE(1, 1);
    asm volatile("s_waitcnt vmcnt(6)" ::: "memory");
    __builtin_amdgcn_s_barrier();
    asm volatile("" ::: "memory");

    for (int t = 0; t < NSTEP; ++t) {
        const int buf = t % 3;
        const int ts  = (t + 2 < NSTEP) ? t + 2 : NSTEP - 1;
        STAGE(ts, (t + 2) % 3);
        __builtin_amdgcn_sched_barrier(0);

        const char* La = (const char*)&lds[buf][0];
        const char* Lb = (const char*)&lds[buf][16384];

        // B frags for this wave's 2 col-groups: f32 LDS -> bf16 regs
        short8 Bf[2];
#pragma unroll
        for (int nf = 0; nf < 2; ++nf) {
            const int nfg = 2 * w + nf;
            f32x4 q0 = *(const f32x4*)(Lb + (nfg * 2 + 0) * 1024 + lane * 16);
            f32x4 q1 = *(const f32x4*)(Lb + (nfg * 2 + 1) * 1024 + lane * 16);
#pragma unroll
            for (int jj = 0; jj < 4; ++jj) {
                Bf[nf][jj]     = (short)f2b(q0[jj]);
                Bf[nf][jj + 4] = (short)f2b(q1[jj]);
            }
        }
        __builtin_amdgcn_s_setprio(1);
#pragma unroll
        for (int a = 0; a < 16; ++a) {
            short8 Af = *(const short8*)(La + a * 1024 + lane * 16);
            acc[a][0] = __builtin_amdgcn_mfma_f32_16x16x32_bf16(Af, Bf[0], acc[a][0], 0, 0, 0);
            acc[a][1] = __builtin_amdgcn_mfma_f32_16x16x32_bf16(Af, Bf[1], acc[a][1], 0, 0, 0);
        }
        __builtin_amdgcn_s_setprio(0);

        // retire stage(t+1) (keep stage(t+2)'s 6 in flight); next buf ready
        asm volatile("s_waitcnt vmcnt(6)" ::: "memory");
        __builtin_amdgcn_s_barrier();
        asm volatile("" ::: "memory");
    }
#undef STAGE

    // ---- partial store (bf16): D row=(l>>4)*4+rr -> batch, col=l&15
    unsigned short* p = part + (long)ks * (BATCH * DIM);
    const int pcol = n0 + 32 * w + (lane & 15);
#pragma unroll
    for (int a = 0; a < 16; ++a) {
        const int prow = 16 * a + (lane >> 4) * 4;
#pragma unroll
        for (int nf = 0; nf < 2; ++nf) {
#pragma unroll
            for (int rr = 0; rr < 4; ++rr)
                p[(long)(prow + rr) * DIM + pcol + nf * 16] = f2b(acc[a][nf][rr]);
        }
    }
}

// ---- reduce: out = sum of 8 bf16 partials (f32 accumulate) ----
__global__ __launch_bounds__(512) void reduce_kernel(const unsigned short* __restrict__ part,
                                                     float* __restrict__ out) {
    long i = (long)blockIdx.x * 512 + threadIdx.x;   // u16x8 index, 262144 total
    const long stride8 = (long)BATCH * DIM / 8;
    const u16x8* p = reinterpret_cast<const u16x8*>(part);
    float s[8];
#pragma unroll
    for (int j = 0; j < 8; ++j) s[j] = 0.f;
#pragma unroll
    for (int k = 0; k < KSPLIT; ++k) {
        u16x8 v = p[k * stride8 + i];
#pragma unroll
        for (int j = 0; j < 8; ++j) s[j] += b2f(v[j]);
    }
    f32x4 o0 = {s[0], s[1], s[2], s[3]};
    f32x4 o1 = {s[4], s[5], s[6], s[7]};
    reinterpret_cast<f32x4*>(out)[2 * i]     = o0;
    reinterpret_cast<f32x4*>(out)[2 * i + 1] = o1;
}

extern "C" void kernel_launch(void* const* d_in, const int* in_sizes, int n_in,
                              void* d_out, int out_size, void* d_ws, size_t ws_size,
                              hipStream_t stream) {
    const float* x = (const float*)d_in[0];     // [256, 8192] f32
    const float* U = (const float*)d_in[1];     // [8192, 8192] f32
    float* outp = (float*)d_out;                // [256, 8192] f32

    unsigned short* xb = (unsigned short*)d_ws;                              // 4 MB
    unsigned short* part = (unsigned short*)((char*)d_ws + (size_t)BATCH * DIM * 2); // 32 MB bf16

    cvt_x_kernel<<<(BATCH * DIM / 4) / 512, 512, 0, stream>>>(x, xb);
    gemm_kernel<<<NTILE * KSPLIT, 512, 0, stream>>>(xb, U, part);
    reduce_kernel<<<(BATCH * DIM / 8) / 512, 512, 0, stream>>>(part, outp);
}